// Round 8
// baseline (57.584 us; speedup 1.0000x reference)
//
#include <hip/hip_runtime.h>

#define NB    4
#define NPB   8192
#define NPTS  (NB*NPB)      // 32768
#define KNB   32
#define CH    64
#define W1C   67
#define GRPS  8
#define EPSV  1e-5f
#define SLOPEV 0.1f

typedef float f32x2 __attribute__((ext_vector_type(2)));
typedef float f32x4 __attribute__((ext_vector_type(4)));
typedef short bf16x8 __attribute__((ext_vector_type(8)));
typedef unsigned short u16;
typedef u16 u16x4 __attribute__((ext_vector_type(4)));
typedef u16 u16x8 __attribute__((ext_vector_type(8)));

// workspace layout (float offsets) — all big buffers bf16
#define WS_STATS1 0
#define WS_STATS2 64
#define WS_STATS3 128
#define WS_FLAG   192          // int flag: 1 => edges are int32
#define WS_YB     256                        // bf16 Y, later bf16 z2pre
#define WS_MX     (WS_YB + NPTS*CH/2)        // bf16 Mx, later bf16 z3pre
#define WS_MN     (WS_MX + NPTS*CH/2)        // bf16 Mn

#define LDP 72                 // padded LDS row stride (bf16 elems) for k_mm

__device__ __forceinline__ u16 f2bf(float f) {
    unsigned u = __float_as_uint(f);
    u += 0x7fff + ((u >> 16) & 1);          // round-nearest-even
    return (u16)(u >> 16);
}
__device__ __forceinline__ float bf2f(u16 h) {
    return __uint_as_float(((unsigned)h) << 16);
}

// ---------------------------------------------------------------- MFMA matmul family
// 64 points/block (512 blocks -> 2 blocks/CU for latency hiding)
// MODE 0: YB(bf16) = sig * W1s^T   (+ edge-dtype probe + stats zeroing in block 0)
// MODE 1: Z2B(bf16) = GN1(lrelu,max/min-select) * W2^T; stats2   (X0=Mx bf16, X1=Mn bf16)
// MODE 2: Z3B(bf16) = GN2(lrelu) * W3^T; stats3                  (X0=Z2B bf16)
template<int MODE>
__global__ __launch_bounds__(256) void k_mm(
    const void* __restrict__ X0,
    const void* __restrict__ X1,
    const float* __restrict__ Wg,
    const float* __restrict__ statsIn, float invcnt,
    const float* __restrict__ gm, const float* __restrict__ bt,
    void* __restrict__ Out,
    float* __restrict__ statsOut,      // MODE 0: ws base (zero 192 floats)
    const int* __restrict__ e_i32, int* __restrict__ flag)
{
    __shared__ u16 Al[64*LDP];
    __shared__ u16 Wl[64*LDP];
    __shared__ float affA[64], affB[64];
    __shared__ float lacc[16];
    __shared__ int sfnd[4];
    int tid = threadIdx.x;
    int pbase = blockIdx.x * 64;
    int b = pbase >> 13;                      // batch index (NPB = 8192)

    if (MODE == 0 && blockIdx.x == 0) {
        if (tid < 192) statsOut[tid] = 0.f;   // zero stats1/2/3 (stream-ordered, race-free)
        // probe: odd dwords of the first 8192 dwords. int64 => high words all 0.
        int found = 0;
        #pragma unroll
        for (int i = 0; i < 16; ++i) {
            int idx = ((tid << 4) + i) * 2 + 1;
            found |= (e_i32[idx] != 0);
        }
        unsigned long long bl = __ballot(found);
        if ((tid & 63) == 0) sfnd[tid >> 6] = (bl != 0ull) ? 1 : 0;
    }
    if (MODE != 0) {
        if (tid < 64) {
            int g = tid >> 3;
            float sv = statsIn[b*16 + g*2 + 0];
            float qv = statsIn[b*16 + g*2 + 1];
            float mean = sv * invcnt;
            float var  = fmaf(-mean, mean, qv * invcnt);
            float rstd = rsqrtf(var + EPSV);
            float a = gm[tid] * rstd;
            affA[tid] = a;
            affB[tid] = fmaf(-mean, a, bt[tid]);
        }
    }
    if (tid < 16) lacc[tid] = 0.f;
    __syncthreads();
    if (MODE == 0 && blockIdx.x == 0 && tid == 0)
        *flag = sfnd[0] | sfnd[1] | sfnd[2] | sfnd[3];

    // ---- stage W (bf16): Wl[o][m] = W[o][m]
    {
        const int wstride = (MODE == 0) ? W1C : 64;
        #pragma unroll
        for (int i = 0; i < 16; ++i) {
            int e = tid + 256*i;
            int o = e >> 6, m = e & 63;
            Wl[o*LDP + m] = f2bf(Wg[o*wstride + m]);
        }
    }
    // ---- stage A (bf16): activated input rows (64 pts x 64 ch / 256 thr = 16 elems)
    #pragma unroll
    for (int it = 0; it < 4; ++it) {
        int fi = it*1024 + tid*4;
        int p = fi >> 6;                      // 0..63
        int m = fi & 63;
        float xv[4];
        if (MODE == 1) {
            u16x4 vx = *(const u16x4*)&((const u16*)X0)[(pbase+p)*64 + m];
            u16x4 vn = *(const u16x4*)&((const u16*)X1)[(pbase+p)*64 + m];
            #pragma unroll
            for (int j = 0; j < 4; ++j) {
                float a = affA[m+j];
                float x = (a < 0.f) ? bf2f(vn[j]) : bf2f(vx[j]);
                float z = fmaf(a, x, affB[m+j]);
                xv[j] = (z >= 0.f) ? z : SLOPEV * z;
            }
        } else if (MODE == 2) {
            u16x4 vh = *(const u16x4*)&((const u16*)X0)[(pbase+p)*64 + m];
            #pragma unroll
            for (int j = 0; j < 4; ++j) {
                float z = fmaf(affA[m+j], bf2f(vh[j]), affB[m+j]);
                xv[j] = (z >= 0.f) ? z : SLOPEV * z;
            }
        } else {
            f32x4 vx = *(const f32x4*)&((const float*)X0)[(pbase+p)*64 + m];
            #pragma unroll
            for (int j = 0; j < 4; ++j) xv[j] = vx[j];
        }
        #pragma unroll
        for (int j = 0; j < 4; ++j)
            Al[p*LDP + m + j] = f2bf(xv[j]);
    }
    __syncthreads();

    // ---- fragments + MFMA: wave w owns points [w*16, w*16+16), all 64 outputs
    int l = tid & 63, w = tid >> 6;
    int lr = l & 15;                          // row/col within tile
    int lk = l >> 4;                          // k-group (0..3)
    bf16x8 af[2], bw[4][2];
    #pragma unroll
    for (int kh = 0; kh < 2; ++kh)
        af[kh] = *(const bf16x8*)&Al[(w*16 + lr)*LDP + kh*32 + lk*8];
    #pragma unroll
    for (int ot = 0; ot < 4; ++ot)
        #pragma unroll
        for (int kh = 0; kh < 2; ++kh)
            bw[ot][kh] = *(const bf16x8*)&Wl[(ot*16 + lr)*LDP + kh*32 + lk*8];

    f32x4 acc[4];
    #pragma unroll
    for (int ot = 0; ot < 4; ++ot) {
        f32x4 c = {0.f, 0.f, 0.f, 0.f};
        c = __builtin_amdgcn_mfma_f32_16x16x32_bf16(af[0], bw[ot][0], c, 0, 0, 0);
        c = __builtin_amdgcn_mfma_f32_16x16x32_bf16(af[1], bw[ot][1], c, 0, 0, 0);
        acc[ot] = c;
    }

    // ---- store C (bf16): row = lk*4 + r, col = lr
    #pragma unroll
    for (int ot = 0; ot < 4; ++ot)
        #pragma unroll
        for (int r = 0; r < 4; ++r) {
            int p = pbase + w*16 + lk*4 + r;
            int o = ot*16 + lr;
            ((u16*)Out)[p*64 + o] = f2bf(acc[ot][r]);
        }

    // ---- fused next-GN stats (f32 accs, pre-quantization)
    if (MODE != 0) {
        #pragma unroll
        for (int ot = 0; ot < 4; ++ot) {
            float s = 0.f, ss = 0.f;
            #pragma unroll
            for (int r = 0; r < 4; ++r) {
                float v = acc[ot][r];
                s += v;
                ss = fmaf(v, v, ss);
            }
            s += __shfl_xor(s, 16, 64);  ss += __shfl_xor(ss, 16, 64);
            s += __shfl_xor(s, 32, 64);  ss += __shfl_xor(ss, 32, 64);
            s += __shfl_xor(s, 1, 64);   ss += __shfl_xor(ss, 1, 64);
            s += __shfl_xor(s, 2, 64);   ss += __shfl_xor(ss, 2, 64);
            s += __shfl_xor(s, 4, 64);   ss += __shfl_xor(ss, 4, 64);
            if ((l & 7) == 0 && l < 16) {
                int g = ot*2 + (l >> 3);
                atomicAdd(&lacc[g*2 + 0], s);
                atomicAdd(&lacc[g*2 + 1], ss);
            }
        }
        __syncthreads();
        if (tid < 16)
            atomicAdd(&statsOut[b*16 + tid], lacc[tid]);
    }
}

// ---------------------------------------------------------------- edge pass
// 8 points/wave, LDS-staged {c0,c1,c2,byteoff}, packed f32x2 math, bf16 Mx/Mn out.
#define PPB_E 32
#define SEDS  (KNB*4 + 4)      // per-point float stride in sed: banks decorrelate across pts
__global__ __launch_bounds__(256) void k_edge(const u16* __restrict__ Yb,
    const void* __restrict__ edg, const float* __restrict__ ef,
    const float* __restrict__ W1, const int* __restrict__ flag,
    u16* __restrict__ Mx, u16* __restrict__ Mn, float* __restrict__ stats1)
{
    __shared__ float sed[PPB_E*SEDS];
    __shared__ float lacc[16];
    int tid = threadIdx.x;
    if (tid < 16) lacc[tid] = 0.f;

    // ---- stage edges+coords, precompute Y byte offsets
    {
        bool is32 = (*flag != 0);
        const int*       e32 = (const int*)edg;
        const long long* e64 = (const long long*)edg;
        int ebase = blockIdx.x * (PPB_E*KNB);
        #pragma unroll
        for (int i = 0; i < 4; ++i) {
            int idx = tid + i*256;            // 0..1023 = pt*KNB + k
            int gi  = ebase + idx;
            int e   = is32 ? __builtin_nontemporal_load(e32 + gi)
                           : (int)__builtin_nontemporal_load(e64 + gi);
            int pt = idx >> 5, k = idx & 31;
            float* d = &sed[pt*SEDS + k*4];
            d[0] = __builtin_nontemporal_load(ef + gi*3 + 0);
            d[1] = __builtin_nontemporal_load(ef + gi*3 + 1);
            d[2] = __builtin_nontemporal_load(ef + gi*3 + 2);
            d[3] = __int_as_float(e << 7);    // e * 128 bytes (64 ch * 2B)
        }
    }

    int lane = tid & 63, wv = tid >> 6;
    int il = lane & 7;                // channel octet = GN group
    int g8 = lane >> 3;               // point slot 0..7
    int lpt = wv*8 + g8;              // local point 0..31
    int p = blockIdx.x * PPB_E + lpt;

    f32x2 w0[4], w1[4], w2[4], yp[4], mx[4], mn[4];
    #pragma unroll
    for (int jj = 0; jj < 4; ++jj) {
        int ch = il*8 + jj*2;
        w0[jj] = (f32x2){W1[ch*W1C + 64], W1[(ch+1)*W1C + 64]};
        w1[jj] = (f32x2){W1[ch*W1C + 65], W1[(ch+1)*W1C + 65]};
        w2[jj] = (f32x2){W1[ch*W1C + 66], W1[(ch+1)*W1C + 66]};
    }
    u16x8 yh = *(const u16x8*)&Yb[p*64 + il*8];
    #pragma unroll
    for (int jj = 0; jj < 4; ++jj) {
        yp[jj] = (f32x2){bf2f(yh[jj*2]), bf2f(yh[jj*2+1])};
        mx[jj] = (f32x2){-3.4e38f, -3.4e38f};
        mn[jj] = (f32x2){ 3.4e38f,  3.4e38f};
    }
    f32x2 s2 = {0.f, 0.f}, ss2 = {0.f, 0.f};
    __syncthreads();

    const char* Ybase = (const char*)Yb + il*16;
    const float* sp = &sed[lpt*SEDS];
    #pragma unroll 8
    for (int k = 0; k < KNB; ++k) {
        f32x4 m4 = *(const f32x4*)(sp + k*4);
        u16x8 q = *(const u16x8*)(Ybase + __float_as_int(m4[3]));
        f32x2 c0v = m4[0], c1v = m4[1], c2v = m4[2];
        #pragma unroll
        for (int jj = 0; jj < 4; ++jj) {
            f32x2 qq = {bf2f(q[jj*2]), bf2f(q[jj*2+1])};
            f32x2 t = qq - yp[jj];
            t = __builtin_elementwise_fma(c0v, w0[jj], t);
            t = __builtin_elementwise_fma(c1v, w1[jj], t);
            t = __builtin_elementwise_fma(c2v, w2[jj], t);
            mx[jj] = __builtin_elementwise_max(mx[jj], t);
            mn[jj] = __builtin_elementwise_min(mn[jj], t);
            s2 += t;
            ss2 = __builtin_elementwise_fma(t, t, ss2);
        }
    }

    u16x8 hx, hn;
    #pragma unroll
    for (int jj = 0; jj < 4; ++jj) {
        hx[jj*2] = f2bf(mx[jj].x); hx[jj*2+1] = f2bf(mx[jj].y);
        hn[jj*2] = f2bf(mn[jj].x); hn[jj*2+1] = f2bf(mn[jj].y);
    }
    __builtin_nontemporal_store(hx, (u16x8*)(Mx + p*64 + il*8));
    __builtin_nontemporal_store(hn, (u16x8*)(Mn + p*64 + il*8));

    float s  = s2.x + s2.y;
    float ss = ss2.x + ss2.y;
    // s,ss are complete sums for GN group il of this point; reduce across the 8 point-slots
    s += __shfl_xor(s,  8, 64);  ss += __shfl_xor(ss,  8, 64);
    s += __shfl_xor(s, 16, 64);  ss += __shfl_xor(ss, 16, 64);
    s += __shfl_xor(s, 32, 64);  ss += __shfl_xor(ss, 32, 64);
    if (lane < 8) {
        atomicAdd(&lacc[lane*2 + 0], s);
        atomicAdd(&lacc[lane*2 + 1], ss);
    }
    __syncthreads();
    if (tid < 16) {
        int b = (blockIdx.x * PPB_E) / NPB;
        atomicAdd(&stats1[b*16 + tid], lacc[tid]);
    }
}

// ---------------------------------------------------------------- final GN + lrelu -> out (bf16 in, f32 out)
__global__ __launch_bounds__(256) void k_out(const u16* __restrict__ Vpre,
    const float* __restrict__ stats, float invcnt,
    const float* __restrict__ gm, const float* __restrict__ bt,
    float* __restrict__ out)
{
    int idx = blockIdx.x * blockDim.x + threadIdx.x;   // one float4 per thread
    int p  = idx >> 4;
    int m0 = (idx & 15) << 2;
    int b  = p >> 13;                                  // p / 8192
    int g  = m0 >> 3;
    float sv = stats[b*16 + g*2 + 0];
    float qv = stats[b*16 + g*2 + 1];
    float mean = sv * invcnt;
    float var  = fmaf(-mean, mean, qv * invcnt);
    float rstd = rsqrtf(var + EPSV);
    u16x4 v = *(const u16x4*)&Vpre[idx*4];
    float r[4];
    #pragma unroll
    for (int j = 0; j < 4; ++j) {
        float aa = gm[m0+j] * rstd;
        float z  = fmaf(aa, bf2f(v[j]) - mean, bt[m0+j]);
        r[j] = (z >= 0.f) ? z : SLOPEV * z;
    }
    f32x4 o4 = {r[0], r[1], r[2], r[3]};
    *(f32x4*)&out[idx*4] = o4;
}

// ---------------------------------------------------------------- launch
extern "C" void kernel_launch(void* const* d_in, const int* in_sizes, int n_in,
                              void* d_out, int out_size, void* d_ws, size_t ws_size,
                              hipStream_t stream)
{
    const float* sig = (const float*)d_in[0];
    const void*  edg = d_in[1];
    const float* ef  = (const float*)d_in[2];
    const float* W1  = (const float*)d_in[3];
    const float* g1  = (const float*)d_in[4];
    const float* b1  = (const float*)d_in[5];
    const float* W2  = (const float*)d_in[6];
    const float* g2  = (const float*)d_in[7];
    const float* b2  = (const float*)d_in[8];
    const float* W3  = (const float*)d_in[9];
    const float* g3  = (const float*)d_in[10];
    const float* b3  = (const float*)d_in[11];
    float* out = (float*)d_out;
    float* ws  = (float*)d_ws;
    u16*   yb  = (u16*)(ws + WS_YB);
    u16*   mxb = (u16*)(ws + WS_MX);
    u16*   mnb = (u16*)(ws + WS_MN);

    k_mm<0><<<NPTS/64, 256, 0, stream>>>(sig, nullptr, W1, nullptr, 0.f,
                                          nullptr, nullptr, yb, ws,
                                          (const int*)edg, (int*)(ws + WS_FLAG));
    k_edge<<<NPTS/PPB_E, 256, 0, stream>>>(yb, edg, ef, W1,
                                           (const int*)(ws + WS_FLAG),
                                           mxb, mnb, ws + WS_STATS1);
    k_mm<1><<<NPTS/64, 256, 0, stream>>>(mxb, mnb, W2,
                                          ws + WS_STATS1, 1.f/(float)(NPB*KNB*8),
                                          g1, b1, yb, ws + WS_STATS2,
                                          nullptr, nullptr);
    k_mm<2><<<NPTS/64, 256, 0, stream>>>(yb, nullptr, W3,
                                          ws + WS_STATS2, 1.f/(float)(NPB*8),
                                          g2, b2, mxb, ws + WS_STATS3,
                                          nullptr, nullptr);
    k_out<<<(NPTS*CH/4)/256, 256, 0, stream>>>(mxb, ws + WS_STATS3,
                                         1.f/(float)(NPB*8), g3, b3, out);
}